// Round 13
// baseline (291.745 us; speedup 1.0000x reference)
//
#include <hip/hip_runtime.h>
#include <math.h>

#define NB 8
#define NP 512
#define NF 512
#define NH 64
#define NW 64
#define FEXPAND 0.02f
#define FEPS 1e-10f

#define IMG_OFF 0
#define PROB_OFF (NB*NH*NW*3)            /* 98304  */
#define NRM_OFF  (PROB_OFF + NB*NH*NW)   /* 131072 */
#define MASK_OFF (NRM_OFF + NB*NF*3)     /* 143360 */

// d_ws layout (floats): partials SoA comp c in 0..5 at c*C + ((T*16+s)*64+lane),
// C = 512*16*64. Tile counters (ints) at CNT0. Records (28 fl/face) at REC0.
#define PARTC (512*16*64)
#define CNT0  3200000
#define REC0  4194304

// 2-kernel pipeline, bit-identical outputs to r10/r11 (both passed):
//  1) face_setup (r11 verbatim): 28-float records ONCE to ws + normals to out
//     + zero per-tile counters.
//  2) raster: 2048 blocks x 256 thr; tile T=bid>>2, wave w -> slice (bid&3)*4+w
//     (ascending slice/list order == r10/r11 -> same bits). Stages hot-16
//     floats/face into 32KB LDS (fixes r11's global-scan latency), bins from
//     LDS (r11's compaction), scans from LDS with r10's bbox-only prefetch
//     (r12's deep pipeline REGRESSED - reverted), needd-path cold fields from
//     L2, partials to ws, then per-thread threadfence + per-tile atomicAdd;
//     4th block merges (r11's exact fold). 2048 short blocks @ 4/CU resident
//     -> queue rebalancing kills the per-tile-L tail (r12's 2.3%-occupancy
//     cold row was the tail signature).
// Exactness invariants (verified r4..r11): pcam/screen/det/valid exact
// __f*_rn no-FMA; normal1 FMA-contracted cross (XLA); sign-precheck ==
// (w0>=0&&w1>=0); covered->prod=0 latch; winner w at z-update; ascending
// slice fold with (oz>bz)||(oz==bz&&of<bf).
__global__ __launch_bounds__(256) void face_setup(
    const float* __restrict__ verts, const int* __restrict__ faces,
    const float* __restrict__ rot, const float* __restrict__ pos,
    const float* __restrict__ proj, float* __restrict__ ws,
    float* __restrict__ out)
{
  int t = blockIdx.x * 256 + threadIdx.x;
  if (t >= NB * NF) return;
  if (t < 512) ((int*)ws)[CNT0 + t] = 0;
  int b = t >> 9;
  float p0 = proj[0], p1 = proj[1], p2 = proj[2];
  float R0=rot[b*9+0],R1=rot[b*9+1],R2=rot[b*9+2];
  float R3=rot[b*9+3],R4=rot[b*9+4],R5=rot[b*9+5];
  float R6=rot[b*9+6],R7=rot[b*9+7],R8=rot[b*9+8];
  float ppx=pos[b*3+0], ppy=pos[b*3+1], ppz=pos[b*3+2];
  int idxs[3] = { faces[t*3+0], faces[t*3+1], faces[t*3+2] };
  float X[3],Y[3],Z[3],SX[3],SY[3];
#pragma unroll
  for (int k = 0; k < 3; ++k) {
    const float* v = verts + ((size_t)b*NP + idxs[k])*3;
    float dx = v[0]-ppx, dy = v[1]-ppy, dz = v[2]-ppz;
    float pcx = __fadd_rn(__fadd_rn(__fmul_rn(R0,dx),__fmul_rn(R1,dy)),__fmul_rn(R2,dz));
    float pcy = __fadd_rn(__fadd_rn(__fmul_rn(R3,dx),__fmul_rn(R4,dy)),__fmul_rn(R5,dz));
    float pcz = __fadd_rn(__fadd_rn(__fmul_rn(R6,dx),__fmul_rn(R7,dy)),__fmul_rn(R8,dz));
    X[k]=pcx; Y[k]=pcy; Z[k]=pcz;
    float dn = __fmul_rn(pcz, p2);
    SX[k] = __fdiv_rn(__fmul_rn(pcx, p0), dn);
    SY[k] = __fdiv_rn(__fmul_rn(pcy, p1), dn);
  }
  float e1x=X[1]-X[0], e1y=Y[1]-Y[0], e1z=Z[1]-Z[0];
  float e2x=X[2]-X[0], e2y=Y[2]-Y[0], e2z=Z[2]-Z[0];
  float nzel = __fsub_rn(__fmul_rn(e1x,e2y), __fmul_rn(e1y,e2x));
  float m0 = __fmul_rn(e1z, e2y); float nxf = __fmaf_rn(e1y, e2z, -m0);
  float m1 = __fmul_rn(e1x, e2z); float nyf = __fmaf_rn(e1z, e2x, -m1);
  float m2 = __fmul_rn(e1y, e2x); float nzf = __fmaf_rn(e1x, e2y, -m2);
  float nn = __fsqrt_rn(__fadd_rn(__fadd_rn(__fmul_rn(nxf,nxf),__fmul_rn(nyf,nyf)),
                                  __fmul_rn(nzf,nzf)));
  float den = __fadd_rn(nn, 1e-12f);
  out[NRM_OFF + (size_t)t*3+0] = __fdiv_rn(nxf, den);
  out[NRM_OFF + (size_t)t*3+1] = __fdiv_rn(nyf, den);
  out[NRM_OFF + (size_t)t*3+2] = __fdiv_rn(nzf, den);

  float ax=SX[0],ay=SY[0],bx=SX[1],by=SY[1],cx=SX[2],cy=SY[2];
  float det = __fadd_rn(__fmul_rn(__fsub_rn(by,cy),__fsub_rn(ax,cx)),
                        __fmul_rn(__fsub_rn(cx,bx),__fsub_rn(ay,cy)));
  float det_safe = (fabsf(det) < FEPS) ? FEPS : det;
  float validf = ((nzel > 0.0f) && (fabsf(det) > FEPS)) ? 1.0f : 0.0f;
  float* d = ws + REC0 + (size_t)t*28;
  d[0]=__fsub_rn(by,cy); d[1]=__fsub_rn(cx,bx);
  d[2]=__fsub_rn(cy,ay); d[3]=__fsub_rn(ax,cx);
  d[4]=cx; d[5]=cy; d[6]=det_safe; d[7]=validf;
  d[8]=Z[0]; d[9]=Z[1]; d[10]=Z[2];
  float vx=bx-ax, vy=by-ay;
  d[11]=1.0f/(vx*vx+vy*vy+1e-12f);
  d[20]=vx; d[21]=vy;
  d[12]=fminf(fminf(ax,bx),cx)-FEXPAND; d[13]=fmaxf(fmaxf(ax,bx),cx)+FEXPAND;
  d[14]=fminf(fminf(ay,by),cy)-FEXPAND; d[15]=fmaxf(fmaxf(ay,by),cy)+FEXPAND;
  d[16]=ax; d[17]=ay; d[18]=bx; d[19]=by;
  vx=cx-bx; vy=cy-by;
  d[22]=vx; d[23]=vy; d[26]=1.0f/(vx*vx+vy*vy+1e-12f);
  vx=ax-cx; vy=ay-cy;
  d[24]=vx; d[25]=vy; d[27]=1.0f/(vx*vx+vy*vy+1e-12f);
}

__global__ __launch_bounds__(256) void raster(
    const float* __restrict__ ws_ro, float* __restrict__ ws,
    const int* __restrict__ faces, const float* __restrict__ colors,
    float* __restrict__ out)
{
  __shared__ __align__(16) float lds[NF*16];   // hot-16/face: 32 KiB
  __shared__ unsigned short flist[NF];
  __shared__ int wcnt[8];
  __shared__ int Ltot;
  __shared__ int oldc;
  int tid  = threadIdx.x;
  int T    = blockIdx.x >> 2;          // tile 0..511
  int q    = blockIdx.x & 3;
  int wave = tid >> 6;                 // 0..3
  int lane = tid & 63;
  int slice = q*4 + wave;              // 0..15
  int b    = T >> 6;
  int txy  = T & 63;
  int ix0 = (txy & 7)*8, iy0 = (txy >> 3)*8;
  int ix = ix0 + (lane & 7);
  int iy = iy0 + (lane >> 3);
  float x = (2.0f*ix + 1.0f - 64.0f) * (1.0f/64.0f);
  float y = (64.0f - 2.0f*iy - 1.0f) * (1.0f/64.0f);
  float txlo = (2.0f*ix0 + 1.0f - 64.0f) * (1.0f/64.0f);
  float txhi = (2.0f*(ix0+7) + 1.0f - 64.0f) * (1.0f/64.0f);
  float tyhi = (64.0f - 2.0f*iy0 - 1.0f) * (1.0f/64.0f);
  float tylo = (64.0f - 2.0f*(iy0+7) - 1.0f) * (1.0f/64.0f);
  const float* recs = ws_ro + REC0 + (size_t)b*NF*28;

  // ---- stage hot-16 floats of all 512 faces into LDS (coalesced) ----
#pragma unroll
  for (int i = 0; i < 8; ++i) {
    int v4 = i*256 + tid;              // float4 index 0..2047
    int f  = v4 >> 2, qd = v4 & 3;
    *(float4*)&lds[f*16 + qd*4] = *(const float4*)(recs + (size_t)f*28 + qd*4);
  }
  __syncthreads();

  // ---- bin: 2 rounds x 4 waves (r11's ascending compaction, bbox from LDS) ----
#pragma unroll
  for (int r = 0; r < 2; ++r) {
    int f = r*256 + tid;
    const float* rr = &lds[f*16 + 12];
    bool pass = (rr[1] >= txlo) && (rr[0] <= txhi) && (rr[3] >= tylo) && (rr[2] <= tyhi);
    unsigned long long m = __ballot(pass);
    if (lane == 0) wcnt[r*4 + wave] = __popcll(m);
    __syncthreads();
    if (pass) {
      int gi = r*4 + wave;
      int off = 0;
#pragma unroll
      for (int i = 0; i < 8; ++i) if (i < gi) off += wcnt[i];
      off += __popcll(m & ((1ull << lane) - 1ull));
      flist[off] = (unsigned short)f;
    }
    __syncthreads();
  }
  if (tid == 0) {
    int s = 0;
#pragma unroll
    for (int i = 0; i < 8; ++i) s += wcnt[i];
    Ltot = s;
  }
  __syncthreads();
  int L = Ltot;

  float bestz = -1e10f;
  int   bestf = 0;
  float bw0 = 0.0f, bw1 = 0.0f, bw2 = 0.0f;
  float prod  = 1.0f;

  // ---- scan (r10-style bbox-only prefetch; hot from LDS, cold from L2) ----
  int idx = slice;
  int fcur = (idx < L) ? (int)flist[idx] : 0;
  float4 bb = (idx < L) ? *(const float4*)&lds[fcur*16 + 12]
                        : make_float4(0.f,0.f,0.f,0.f);
  while (idx < L) {
    int nidx = idx + 16;
    int fnext = fcur;
    float4 bbn = bb;
    if (nidx < L) {
      fnext = (int)flist[nidx];
      bbn = *(const float4*)&lds[fnext*16 + 12];
    }
    int f = fcur;
    bool inb = (x >= bb.x) && (x <= bb.y) && (y >= bb.z) && (y <= bb.w);
    bool covered = false;
    if (__any(inb)) {
      const float* h = &lds[f*16];
      float4 qe = *(const float4*)(h);       // e0x,e0y,e1x,e1y
      float4 q1 = *(const float4*)(h + 4);   // cx,cy,det_safe,validf
      float dxc = x - q1.x, dyc = y - q1.y;
      float n0 = __fadd_rn(__fmul_rn(qe.x, dxc), __fmul_rn(qe.y, dyc));
      float n1 = __fadd_rn(__fmul_rn(qe.z, dxc), __fmul_rn(qe.w, dyc));
      // exact sign-equivalent of (w0>=0 && w1>=0) (verified r9/r10/r11)
      bool dsp  = q1.z > 0.0f;
      bool spass = ((n0 == 0.0f) || ((n0 > 0.0f) == dsp)) &&
                   ((n1 == 0.0f) || ((n1 > 0.0f) == dsp));
      bool act = inb && spass;
      if (__any(act)) {
        float4 q2 = *(const float4*)(h + 8); // za,zb,zc,invAB
        float w0 = __fdiv_rn(n0, q1.z);
        float w1 = __fdiv_rn(n1, q1.z);
        float w2 = __fsub_rn(__fsub_rn(1.0f, w0), w1);
        covered = act && (w2 >= 0.0f);
        bool valid = covered && (q1.w > 0.5f);
        float z = __fadd_rn(__fadd_rn(__fmul_rn(w0,q2.x), __fmul_rn(w1,q2.y)),
                            __fmul_rn(w2,q2.z));
        float zval = valid ? z : -1e10f;
        if (zval > bestz) { bestz = zval; bestf = f; bw0 = w0; bw1 = w1; bw2 = w2; }
      }
      if (covered) prod = 0.0f;              // == prod*(1-exp(-0)) exactly
      bool needd = inb && !covered && (prod != 0.0f);
      if (__any(needd)) {
        const float* g = recs + (size_t)f*28;
        float4 qa = *(const float4*)(g + 16); // ax,ay,bx,by
        float4 qv = *(const float4*)(g + 20); // vABx,vABy,vBCx,vBCy
        float4 qw = *(const float4*)(g + 24); // vCAx,vCAy,invBC,invCA
        float invAB = h[11];
        float dxa = x - qa.x, dya = y - qa.y;
        float t1 = fminf(fmaxf((dxa*qv.x + dya*qv.y)*invAB, 0.0f), 1.0f);
        float rx = dxa - t1*qv.x, ry = dya - t1*qv.y;
        float d2 = rx*rx + ry*ry;
        float dxb = x - qa.z, dyb = y - qa.w;
        t1 = fminf(fmaxf((dxb*qv.z + dyb*qv.w)*qw.z, 0.0f), 1.0f);
        rx = dxb - t1*qv.z; ry = dyb - t1*qv.w;
        d2 = fminf(d2, rx*rx + ry*ry);
        t1 = fminf(fmaxf((dxc*qw.x + dyc*qw.y)*qw.w, 0.0f), 1.0f);
        rx = dxc - t1*qw.x; ry = dyc - t1*qw.y;
        d2 = fminf(d2, rx*rx + ry*ry);
        if (needd)
          prod *= (1.0f - __expf(d2 * -142.85714285714286f));  // -(1e6/7000)*d2
      }
    }
    idx = nidx; fcur = fnext; bb = bbn;
  }

  // ---- partial write (SoA; each wave owns its row) ----
  size_t base = ((size_t)T*16 + slice)*64 + lane;
  ws[(size_t)0*PARTC + base] = bestz;
  ws[(size_t)1*PARTC + base] = __int_as_float(bestf);
  ws[(size_t)2*PARTC + base] = prod;
  ws[(size_t)3*PARTC + base] = bw0;
  ws[(size_t)4*PARTC + base] = bw1;
  ws[(size_t)5*PARTC + base] = bw2;
  __threadfence();                 // make THIS thread's partials device-visible
  __syncthreads();                 // all threads' stores drained (vmcnt(0))
  if (tid == 0) oldc = atomicAdd((int*)ws + CNT0 + T, 1);
  __syncthreads();

  // ---- 4th-arriving block merges the tile (r11's exact fold) ----
  if (oldc == 3 && tid < 64) {
    __threadfence();               // acquire: invalidate stale cached partials
    size_t mb = ((size_t)T*16)*64 + tid;
    float bz = ws[0*(size_t)PARTC + mb]; int bf = __float_as_int(ws[1*(size_t)PARTC + mb]);
    float pr = ws[2*(size_t)PARTC + mb];
    float w0 = ws[3*(size_t)PARTC + mb], w1 = ws[4*(size_t)PARTC + mb], w2 = ws[5*(size_t)PARTC + mb];
    for (int s = 1; s < 16; ++s) {
      size_t o = mb + (size_t)s*64;
      float oz = ws[0*(size_t)PARTC + o]; int of = __float_as_int(ws[1*(size_t)PARTC + o]);
      if (oz > bz || (oz == bz && of < bf)) {
        bz = oz; bf = of; w0 = ws[3*(size_t)PARTC + o]; w1 = ws[4*(size_t)PARTC + o]; w2 = ws[5*(size_t)PARTC + o];
      }
      pr *= ws[2*(size_t)PARTC + o];
    }
    int av = (bz != -1e10f);       // valid faces have z in [-5,-1] >> -1e10
    int t = b * NF + bf;
    const int* fi = faces + (size_t)t*3;
    const float* cb = colors + (size_t)b*NP*3;
    int i0 = fi[0], i1 = fi[1], i2 = fi[2];
    float fr  = w0*cb[i0*3+0] + w1*cb[i1*3+0] + w2*cb[i2*3+0];
    float fgc = w0*cb[i0*3+1] + w1*cb[i1*3+1] + w2*cb[i2*3+1];
    float fb  = w0*cb[i0*3+2] + w1*cb[i1*3+2] + w2*cb[i2*3+2];
    float fa  = __fadd_rn(__fadd_rn(w0, w1), w2);
    int gp = b*4096 + iy*64 + ix;  // tid<64 -> wave 0 -> lane==tid
    out[IMG_OFF + (size_t)gp*3 + 0] = av ? fr  : 0.0f;
    out[IMG_OFF + (size_t)gp*3 + 1] = av ? fgc : 0.0f;
    out[IMG_OFF + (size_t)gp*3 + 2] = av ? fb  : 0.0f;
    out[PROB_OFF + gp] = 1.0f - pr;
    out[MASK_OFF + gp] = av ? fa : 0.0f;
  }
}

extern "C" void kernel_launch(void* const* d_in, const int* in_sizes, int n_in,
                              void* d_out, int out_size, void* d_ws, size_t ws_size,
                              hipStream_t stream) {
  const float* verts  = (const float*)d_in[0];
  const int*   faces  = (const int*)  d_in[1];
  const float* rot    = (const float*)d_in[2];
  const float* pos    = (const float*)d_in[3];
  const float* proj   = (const float*)d_in[4];
  const float* colors = (const float*)d_in[5];
  float* out = (float*)d_out;
  float* ws  = (float*)d_ws;

  hipLaunchKernelGGL(face_setup, dim3((NB*NF)/256), dim3(256), 0, stream,
                     verts, faces, rot, pos, proj, ws, out);
  hipLaunchKernelGGL(raster, dim3(512*4), dim3(256), 0, stream,
                     ws, ws, faces, colors, out);
}

// Round 14
// 98.437 us; speedup vs baseline: 2.9638x; 2.9638x over previous
//
#include <hip/hip_runtime.h>
#include <math.h>

#define NB 8
#define NP 512
#define NF 512
#define NH 64
#define NW 64
#define FEXPAND 0.02f
#define FEPS 1e-10f

#define IMG_OFF 0
#define PROB_OFF (NB*NH*NW*3)            /* 98304  */
#define NRM_OFF  (PROB_OFF + NB*NH*NW)   /* 131072 */
#define MASK_OFF (NRM_OFF + NB*NF*3)     /* 143360 */

// r10 skeleton (best measured: 89.5) with setup restructured, LDS-only:
//  - ALL 1024 threads do the 1536 vertex transforms (loop i += 1024) into an
//    LDS scratch (X,Y,Z,SX,SY per face-vertex); ops bit-verbatim (same exact
//    __f*_rn chains, just different executing thread). Threads 0..511 then
//    assemble records from scratch -- every discrete-path value (e0,e1,det,
//    det_safe,validf,bbox,z) from identical op sequences -> identical bits.
//  - records now 16 floats (hot only). The needd (soft-edge, SMOOTH) path
//    derives: vBC=(d1,-d0), vCA=(d3,-d2) EXACT (they are the stored subs);
//    a=(cx+d3, cy-d2), b=(cx-d1, cy+d0), vAB=(-d1-d3, d0+d2) within 1-2ulp;
//    invLs inline. improb shift <=1e-5 << 0.0039 compare floor; coverage/z/
//    argmax unaffected -> imrender/normals/hardmask bit-identical.
//  - r13 lesson: NO global-memory producer/consumer, NO fences. LDS only.
// Exactness invariants (verified r4..r12): pcam/screen/det/valid exact
// __f*_rn no-FMA; normal1 FMA-contracted cross (XLA golden); sign-precheck ==
// (w0>=0 && w1>=0) exactly; covered -> prod=0 latch; winner w at z-update;
// ascending slice order + (oz>bz)||(oz==bz&&of<bf) fold.
// Record (16 floats): [0..3] e0x,e0y,e1x,e1y  [4..7] cx,cy,det_safe,validf
//                     [8..11] za,zb,zc,pad    [12..15] xmin,xmax,ymin,ymax
__global__ __launch_bounds__(1024, 8) void render_all(
    const float* __restrict__ verts, const int* __restrict__ faces,
    const float* __restrict__ rot, const float* __restrict__ pos,
    const float* __restrict__ proj, const float* __restrict__ colors,
    float* __restrict__ out)
{
  __shared__ __align__(16) float recs[NF*16];     // 32 KiB; comb aliased later
  __shared__ float scratch[NF*15];                // 30 KiB; X,Y,Z,SX,SY x3
  __shared__ unsigned short flist[NF];
  __shared__ int wcnt[8];
  __shared__ int Ltot;
  int tid  = threadIdx.x;
  int b    = blockIdx.x >> 6;    // 64 tiles per batch
  int tile = blockIdx.x & 63;
  int wave = tid >> 6;           // 16 waves
  int lane = tid & 63;           // pixel within 8x8 tile
  int ix0 = (tile & 7)*8, iy0 = (tile >> 3)*8;
  int ix = ix0 + (lane & 7);
  int iy = iy0 + (lane >> 3);
  // xs=(2ix+1-64)/64, ys=(64-2iy-1)/64 : all ops exact (pow2 divide)
  float x = (2.0f*ix + 1.0f - 64.0f) * (1.0f/64.0f);
  float y = (64.0f - 2.0f*iy - 1.0f) * (1.0f/64.0f);
  float txlo = (2.0f*ix0 + 1.0f - 64.0f) * (1.0f/64.0f);
  float txhi = (2.0f*(ix0+7) + 1.0f - 64.0f) * (1.0f/64.0f);
  float tyhi = (64.0f - 2.0f*iy0 - 1.0f) * (1.0f/64.0f);
  float tylo = (64.0f - 2.0f*(iy0+7) - 1.0f) * (1.0f/64.0f);

  // ---- phase 1: 1536 vertex transforms across ALL 1024 threads ----
  {
    float p0 = proj[0], p1 = proj[1], p2 = proj[2];
    float R0=rot[b*9+0],R1=rot[b*9+1],R2=rot[b*9+2];
    float R3=rot[b*9+3],R4=rot[b*9+4],R5=rot[b*9+5];
    float R6=rot[b*9+6],R7=rot[b*9+7],R8=rot[b*9+8];
    float ppx=pos[b*3+0], ppy=pos[b*3+1], ppz=pos[b*3+2];
    for (int i = tid; i < 3*NF; i += 1024) {
      int k = i >> 9, f = i & 511;
      int vi = faces[((size_t)(b*NF + f))*3 + k];
      const float* v = verts + ((size_t)b*NP + vi)*3;
      float dx = v[0]-ppx, dy = v[1]-ppy, dz = v[2]-ppz;
      // exact left-to-right, no FMA (verified r4..r12)
      float pcx = __fadd_rn(__fadd_rn(__fmul_rn(R0,dx),__fmul_rn(R1,dy)),__fmul_rn(R2,dz));
      float pcy = __fadd_rn(__fadd_rn(__fmul_rn(R3,dx),__fmul_rn(R4,dy)),__fmul_rn(R5,dz));
      float pcz = __fadd_rn(__fadd_rn(__fmul_rn(R6,dx),__fmul_rn(R7,dy)),__fmul_rn(R8,dz));
      float dn = __fmul_rn(pcz, p2);
      float sx = __fdiv_rn(__fmul_rn(pcx, p0), dn);
      float sy = __fdiv_rn(__fmul_rn(pcy, p1), dn);
      float* s = &scratch[f*15 + k*5];
      s[0]=pcx; s[1]=pcy; s[2]=pcz; s[3]=sx; s[4]=sy;
    }
  }
  __syncthreads();

  // ---- phase 2: assemble records (threads 0..511), normals if tile==0 ----
  if (tid < NF) {
    const float* s = &scratch[tid*15];
    float X0=s[0], Y0=s[1], Z0=s[2], ax=s[3], ay=s[4];
    float X1=s[5], Y1=s[6], Z1=s[7], bx=s[8], by=s[9];
    float X2=s[10],Y2=s[11],Z2=s[12],cx=s[13],cy=s[14];
    float e1x=X1-X0, e1y=Y1-Y0, e1z=Z1-Z0;
    float e2x=X2-X0, e2y=Y2-Y0, e2z=Z2-Z0;
    // valid gate: ELEMENTWISE nz (verified r4..r12)
    float nzel = __fsub_rn(__fmul_rn(e1x,e2y), __fmul_rn(e1y,e2x));
    if (tile == 0) {
      // normal1: FMA-contracted cross (XLA golden; verified r4..r12)
      int t = b * NF + tid;
      float m0 = __fmul_rn(e1z, e2y); float nxf = __fmaf_rn(e1y, e2z, -m0);
      float m1 = __fmul_rn(e1x, e2z); float nyf = __fmaf_rn(e1z, e2x, -m1);
      float m2 = __fmul_rn(e1y, e2x); float nzf = __fmaf_rn(e1x, e2y, -m2);
      float nn = __fsqrt_rn(__fadd_rn(__fadd_rn(__fmul_rn(nxf,nxf),__fmul_rn(nyf,nyf)),
                                      __fmul_rn(nzf,nzf)));
      float den = __fadd_rn(nn, 1e-12f);
      out[NRM_OFF + (size_t)t*3+0] = __fdiv_rn(nxf, den);
      out[NRM_OFF + (size_t)t*3+1] = __fdiv_rn(nyf, den);
      out[NRM_OFF + (size_t)t*3+2] = __fdiv_rn(nzf, den);
    }
    float det = __fadd_rn(__fmul_rn(__fsub_rn(by,cy),__fsub_rn(ax,cx)),
                          __fmul_rn(__fsub_rn(cx,bx),__fsub_rn(ay,cy)));
    float det_safe = (fabsf(det) < FEPS) ? FEPS : det;
    float validf = ((nzel > 0.0f) && (fabsf(det) > FEPS)) ? 1.0f : 0.0f;
    float* d = &recs[tid*16];
    d[0]=__fsub_rn(by,cy); d[1]=__fsub_rn(cx,bx);
    d[2]=__fsub_rn(cy,ay); d[3]=__fsub_rn(ax,cx);
    d[4]=cx; d[5]=cy; d[6]=det_safe; d[7]=validf;
    d[8]=Z0; d[9]=Z1; d[10]=Z2; d[11]=0.0f;
    d[12]=fminf(fminf(ax,bx),cx)-FEXPAND; d[13]=fmaxf(fmaxf(ax,bx),cx)+FEXPAND;
    d[14]=fminf(fminf(ay,by),cy)-FEXPAND; d[15]=fmaxf(fmaxf(ay,by),cy)+FEXPAND;
  }
  __syncthreads();

  // ---- bin (r10 verbatim; ascending compaction) ----
  bool pass = false;
  if (tid < NF) {
    const float* rr = &recs[tid*16 + 12];
    pass = (rr[1] >= txlo) && (rr[0] <= txhi) && (rr[3] >= tylo) && (rr[2] <= tyhi);
  }
  unsigned long long m = __ballot(pass);
  if (tid < NF && (tid & 63) == 0) wcnt[tid >> 6] = __popcll(m);
  __syncthreads();
  if (tid < NF && pass) {
    int w8 = tid >> 6;
    int off = 0;
#pragma unroll
    for (int i = 0; i < 8; ++i) if (i < w8) off += wcnt[i];
    off += __popcll(m & ((1ull << (tid & 63)) - 1ull));
    flist[off] = (unsigned short)tid;
  }
  if (tid == 0) {
    int s = 0;
#pragma unroll
    for (int i = 0; i < 8; ++i) s += wcnt[i];
    Ltot = s;
  }
  __syncthreads();
  int L = Ltot;

  float bestz = -1e10f;
  int   bestf = 0;
  float bw0 = 0.0f, bw1 = 0.0f, bw2 = 0.0f;
  float prod  = 1.0f;

  // ---- scan (r10 verbatim structure; cold fields derived in needd) ----
  int idx = wave;
  int fcur = (idx < L) ? (int)flist[idx] : 0;
  float4 bb = (idx < L) ? *(const float4*)&recs[fcur*16 + 12]
                        : make_float4(0.f,0.f,0.f,0.f);
  while (idx < L) {
    int nidx = idx + 16;
    int fnext = fcur;
    float4 bbn = bb;
    if (nidx < L) {
      fnext = (int)flist[nidx];
      bbn = *(const float4*)&recs[fnext*16 + 12];
    }
    int f = fcur;
    bool inb = (x >= bb.x) && (x <= bb.y) && (y >= bb.z) && (y <= bb.w);
    bool covered = false;
    if (__any(inb)) {
      const float* h = &recs[f*16];
      float4 qe = *(const float4*)(h);       // e0x,e0y,e1x,e1y
      float4 q1 = *(const float4*)(h + 4);   // cx,cy,det_safe,validf
      float dxc = x - q1.x, dyc = y - q1.y;
      float n0 = __fadd_rn(__fmul_rn(qe.x, dxc), __fmul_rn(qe.y, dyc));
      float n1 = __fadd_rn(__fmul_rn(qe.z, dxc), __fmul_rn(qe.w, dyc));
      // exact sign-equivalent of (w0>=0 && w1>=0) (verified r9..r12)
      bool dsp  = q1.z > 0.0f;
      bool spass = ((n0 == 0.0f) || ((n0 > 0.0f) == dsp)) &&
                   ((n1 == 0.0f) || ((n1 > 0.0f) == dsp));
      bool act = inb && spass;
      if (__any(act)) {
        float4 q2 = *(const float4*)(h + 8); // za,zb,zc,pad
        float w0 = __fdiv_rn(n0, q1.z);
        float w1 = __fdiv_rn(n1, q1.z);
        float w2 = __fsub_rn(__fsub_rn(1.0f, w0), w1);
        covered = act && (w2 >= 0.0f);
        bool valid = covered && (q1.w > 0.5f);
        float z = __fadd_rn(__fadd_rn(__fmul_rn(w0,q2.x), __fmul_rn(w1,q2.y)),
                            __fmul_rn(w2,q2.z));
        float zval = valid ? z : -1e10f;
        if (zval > bestz) { bestz = zval; bestf = f; bw0 = w0; bw1 = w1; bw2 = w2; }
      }
      if (covered) prod = 0.0f;              // == prod*(1-exp(-0)) exactly
      bool needd = inb && !covered && (prod != 0.0f);
      if (__any(needd)) {
        // smooth path only: derive geometry from hot record (<=2ulp; improb
        // shift <=1e-5, far under the 0.0039 compare floor)
        float axd = q1.x + qe.w, ayd = q1.y - qe.z;   // a ~= c + (d3,-d2)
        float bxd = q1.x - qe.y, byd = q1.y + qe.x;   // b ~= c - (d1,-d0)
        float vABx = -qe.y - qe.w, vABy = qe.x + qe.z;
        float vBCx = qe.y, vBCy = -qe.x;              // EXACT (stored subs)
        float vCAx = qe.w, vCAy = -qe.z;              // EXACT
        float invAB = 1.0f/(vABx*vABx + vABy*vABy + 1e-12f);
        float invBC = 1.0f/(vBCx*vBCx + vBCy*vBCy + 1e-12f);
        float invCA = 1.0f/(vCAx*vCAx + vCAy*vCAy + 1e-12f);
        float dxa = x - axd, dya = y - ayd;
        float t1 = fminf(fmaxf((dxa*vABx + dya*vABy)*invAB, 0.0f), 1.0f);
        float rx = dxa - t1*vABx, ry = dya - t1*vABy;
        float d2 = rx*rx + ry*ry;
        float dxb = x - bxd, dyb = y - byd;
        t1 = fminf(fmaxf((dxb*vBCx + dyb*vBCy)*invBC, 0.0f), 1.0f);
        rx = dxb - t1*vBCx; ry = dyb - t1*vBCy;
        d2 = fminf(d2, rx*rx + ry*ry);
        t1 = fminf(fmaxf((dxc*vCAx + dyc*vCAy)*invCA, 0.0f), 1.0f);
        rx = dxc - t1*vCAx; ry = dyc - t1*vCAy;
        d2 = fminf(d2, rx*rx + ry*ry);
        if (needd)
          prod *= (1.0f - __expf(d2 * -142.85714285714286f));  // -(1e6/7000)*d2
      }
    }
    idx = nidx; fcur = fnext; bb = bbn;
  }

  __syncthreads();                 // records dead; alias combine buffer
  float* comb = recs;              // [16 slices][64 px][stride 7] = 28 KiB
  float* c = comb + (size_t)(wave*64 + lane)*7;
  c[0]=bestz; c[1]=__int_as_float(bestf); c[2]=prod;
  c[3]=bw0; c[4]=bw1; c[5]=bw2;
  __syncthreads();

  if (tid < 64) {
    const float* c0 = comb + (size_t)tid*7;
    float bz = c0[0]; int bf = __float_as_int(c0[1]); float pr = c0[2];
    float w0 = c0[3], w1 = c0[4], w2 = c0[5];
    for (int s = 1; s < 16; ++s) {
      const float* cs = comb + (size_t)(s*64 + tid)*7;
      float oz = cs[0]; int of = __float_as_int(cs[1]);
      if (oz > bz || (oz == bz && of < bf)) { bz = oz; bf = of; w0 = cs[3]; w1 = cs[4]; w2 = cs[5]; }
      pr *= cs[2];
    }
    int av = (bz != -1e10f);       // valid faces have z in [-5,-1] >> -1e10
    int t = b * NF + bf;
    const int* fi = faces + (size_t)t*3;
    const float* cb = colors + (size_t)b*NP*3;
    int i0 = fi[0], i1 = fi[1], i2 = fi[2];
    float fr  = w0*cb[i0*3+0] + w1*cb[i1*3+0] + w2*cb[i2*3+0];
    float fgc = w0*cb[i0*3+1] + w1*cb[i1*3+1] + w2*cb[i2*3+1];
    float fb  = w0*cb[i0*3+2] + w1*cb[i1*3+2] + w2*cb[i2*3+2];
    float fa  = __fadd_rn(__fadd_rn(w0, w1), w2);
    int gp = b*4096 + iy*64 + ix;  // tid<64 -> wave 0 -> lane==tid
    out[IMG_OFF + (size_t)gp*3 + 0] = av ? fr  : 0.0f;
    out[IMG_OFF + (size_t)gp*3 + 1] = av ? fgc : 0.0f;
    out[IMG_OFF + (size_t)gp*3 + 2] = av ? fb  : 0.0f;
    out[PROB_OFF + gp] = 1.0f - pr;
    out[MASK_OFF + gp] = av ? fa : 0.0f;
  }
}

extern "C" void kernel_launch(void* const* d_in, const int* in_sizes, int n_in,
                              void* d_out, int out_size, void* d_ws, size_t ws_size,
                              hipStream_t stream) {
  const float* verts  = (const float*)d_in[0];
  const int*   faces  = (const int*)  d_in[1];
  const float* rot    = (const float*)d_in[2];
  const float* pos    = (const float*)d_in[3];
  const float* proj   = (const float*)d_in[4];
  const float* colors = (const float*)d_in[5];
  float* out = (float*)d_out;
  (void)d_ws; (void)ws_size;

  hipLaunchKernelGGL(render_all, dim3(NB*64), dim3(1024), 0, stream,
                     verts, faces, rot, pos, proj, colors, out);
}